// Round 1
// baseline (1809.413 us; speedup 1.0000x reference)
//
#include <hip/hip_runtime.h>

// Problem constants (from reference): B=32, T=2048, V=64, H=256, HD=128.
#define BB 32
#define TT 2048
#define VV 64
#define HH 256
#define HD 128
#define G3 384  // 3*HD

// ---------------------------------------------------------------------------
// Kernel 1: gi_table[dir][v][j] = emb[v] @ Wih_dir[j].T + bih_dir[j]
// Only 64 distinct tokens -> the whole input projection is a 64x384 table.
// (bhh is NOT folded: the n-gate needs bhh inside r*(...), added per-step.)
// ---------------------------------------------------------------------------
__global__ __launch_bounds__(G3, 1)
void gi_table_kernel(const float* __restrict__ emb,
                     const float* __restrict__ Wih_f, const float* __restrict__ bih_f,
                     const float* __restrict__ Wih_b, const float* __restrict__ bih_b,
                     float* __restrict__ gi_ws) {
  const int gid = blockIdx.x;          // 0..127
  const int dir = gid >> 6;
  const int v   = gid & 63;
  const int j   = threadIdx.x;         // 0..383
  const float* Wih = dir ? Wih_b : Wih_f;
  const float* bih = dir ? bih_b : bih_f;
  const float4* er = reinterpret_cast<const float4*>(emb + v * HH);
  const float4* wr = reinterpret_cast<const float4*>(Wih + j * HH);
  float acc = bih[j];
  #pragma unroll 8
  for (int k = 0; k < HH / 4; ++k) {
    float4 e = er[k];
    float4 w = wr[k];
    acc = fmaf(e.x, w.x, acc);
    acc = fmaf(e.y, w.y, acc);
    acc = fmaf(e.z, w.z, acc);
    acc = fmaf(e.w, w.w, acc);
  }
  gi_ws[dir * (VV * G3) + v * G3 + j] = acc;
}

// ---------------------------------------------------------------------------
// Kernel 2: the recurrence. One block per (batch, direction) chain: 64 blocks.
// 384 threads: thread j computes gh_j = Whh[j,:] @ h + bhh_j each step, with
// Whh row j held in 128 VGPRs. h lives in LDS (float4 uniform broadcasts).
// Threads 0..127 own h_i: gate math + pooling accumulator in registers.
// Backward direction == forward over the reversed token stream; pooled sum
// needs no un-reversal (sum over valid steps is order-invariant).
// ---------------------------------------------------------------------------
__global__ __launch_bounds__(G3, 1)
void gru_kernel(const int* __restrict__ tokens, const int* __restrict__ lengths,
                const float* __restrict__ Whh_f, const float* __restrict__ bhh_f,
                const float* __restrict__ Whh_b, const float* __restrict__ bhh_b,
                const float* __restrict__ gi_ws, float* __restrict__ out) {
  __shared__ float  giL[VV * G3];   // 96 KB: gi table for this direction
  __shared__ int    tokL[TT];       // 8 KB: token stream (pre-reversed if bwd)
  __shared__ float  ghL[G3];        // per-step gh results
  __shared__ float4 hbuf4[HD / 4];  // current h state, float4 for broadcast reads

  const int bid = blockIdx.x;       // 0..63
  const int b   = bid & 31;
  const int dir = bid >> 5;
  const int j   = threadIdx.x;      // 0..383
  int len = lengths[b];
  if (len < 1) len = 1;

  // Stage gi table (coalesced; 64 rows of 384 floats).
  const float* gi_src = gi_ws + dir * (VV * G3);
  for (int idx = j; idx < VV * G3; idx += G3) giL[idx] = gi_src[idx];

  // Stage tokens, reversed in-place for the backward direction.
  const int* tb = tokens + b * TT;
  for (int s = j; s < len; s += G3) tokL[s] = tb[dir ? (len - 1 - s) : s];

  // Whh row j -> 128 VGPRs (reused for all `len` steps).
  const float* Whh = dir ? Whh_b : Whh_f;
  const float* bhh = dir ? bhh_b : bhh_f;
  float w[HD];
  {
    const float4* wr = reinterpret_cast<const float4*>(Whh + j * HD);
    #pragma unroll
    for (int k = 0; k < HD / 4; ++k) {
      float4 t = wr[k];
      w[4 * k + 0] = t.x;
      w[4 * k + 1] = t.y;
      w[4 * k + 2] = t.z;
      w[4 * k + 3] = t.w;
    }
  }
  const float bh = bhh[j];

  float h = 0.0f, hsum = 0.0f;
  if (j < HD) reinterpret_cast<float*>(hbuf4)[j] = 0.0f;
  __syncthreads();

  for (int s = 0; s < len; ++s) {
    // gh_j = Whh[j,:] @ h + bhh_j  (h via LDS float4 broadcasts)
    float acc = bh;
    #pragma unroll
    for (int k4 = 0; k4 < HD / 4; ++k4) {
      float4 hv = hbuf4[k4];
      acc = fmaf(w[4 * k4 + 0], hv.x, acc);
      acc = fmaf(w[4 * k4 + 1], hv.y, acc);
      acc = fmaf(w[4 * k4 + 2], hv.z, acc);
      acc = fmaf(w[4 * k4 + 3], hv.w, acc);
    }
    ghL[j] = acc;
    __syncthreads();

    if (j < HD) {
      const int tok = tokL[s];                 // uniform -> LDS broadcast
      const float* gi = giL + tok * G3;
      const float ghr = acc;                   // own value: j < 128 is the r range
      const float ghz = ghL[HD + j];
      const float ghn = ghL[2 * HD + j];
      const float r = 1.0f / (1.0f + __expf(-(gi[j] + ghr)));
      const float z = 1.0f / (1.0f + __expf(-(gi[HD + j] + ghz)));
      const float n = tanhf(gi[2 * HD + j] + r * ghn);
      h = (1.0f - z) * n + z * h;
      hsum += h;
      reinterpret_cast<float*>(hbuf4)[j] = h;
    }
    __syncthreads();
  }

  if (j < HD) {
    out[b * HH + dir * HD + j] = hsum / (float)len;
  }
}

// ---------------------------------------------------------------------------
extern "C" void kernel_launch(void* const* d_in, const int* in_sizes, int n_in,
                              void* d_out, int out_size, void* d_ws, size_t ws_size,
                              hipStream_t stream) {
  const int*   tokens = (const int*)d_in[0];
  const int*   lengths = (const int*)d_in[1];
  const float* emb    = (const float*)d_in[2];
  const float* Wih_f  = (const float*)d_in[3];
  const float* Whh_f  = (const float*)d_in[4];
  const float* bih_f  = (const float*)d_in[5];
  const float* bhh_f  = (const float*)d_in[6];
  const float* Wih_b  = (const float*)d_in[7];
  const float* Whh_b  = (const float*)d_in[8];
  const float* bih_b  = (const float*)d_in[9];
  const float* bhh_b  = (const float*)d_in[10];
  float* out = (float*)d_out;
  float* gi_ws = (float*)d_ws;  // needs 2*64*384*4 = 192 KB

  gi_table_kernel<<<2 * VV, G3, 0, stream>>>(emb, Wih_f, bih_f, Wih_b, bih_b, gi_ws);
  gru_kernel<<<2 * BB, G3, 0, stream>>>(tokens, lengths, Whh_f, bhh_f, Whh_b, bhh_b,
                                        gi_ws, out);
}

// Round 2
// 970.793 us; speedup vs baseline: 1.8638x; 1.8638x over previous
//
#include <hip/hip_runtime.h>

// Problem constants: B=32, T=2048, V=64, H=256, HD=128.
#define BB 32
#define TT 2048
#define VV 64
#define HH 256
#define HD 128
#define G3 384  // 3*HD

// ---------------------------------------------------------------------------
// Fast gate math: v_exp_f32 + v_rcp_f32 (~1 ulp each; threshold is 3.8e-3).
// ---------------------------------------------------------------------------
__device__ __forceinline__ float fsigmoid(float x) {
  // exp(-x) -> inf for very negative x; rcp(inf)=0 -> sigmoid->0. No NaN path.
  return __builtin_amdgcn_rcpf(1.0f + __expf(-x));
}
__device__ __forceinline__ float ftanh(float x) {
  // Compute on |x| so exp argument is <= 0 (no overflow), restore sign.
  float ax = fabsf(x);
  float t = __expf(-2.0f * ax);  // in (0,1]
  float r = 1.0f - 2.0f * t * __builtin_amdgcn_rcpf(1.0f + t);
  return copysignf(r, x);
}

// Quad (lanes 4u..4u+3) sum via DPP quad_perm adds — VALU pipe, all 4 lanes
// end with the full sum. quad_perm[1,0,3,2]=0xB1, quad_perm[2,3,0,1]=0x4E.
__device__ __forceinline__ float quad_reduce_add(float v) {
  int x = __builtin_amdgcn_mov_dpp(__float_as_int(v), 0xB1, 0xF, 0xF, true);
  v += __int_as_float(x);
  x = __builtin_amdgcn_mov_dpp(__float_as_int(v), 0x4E, 0xF, 0xF, true);
  v += __int_as_float(x);
  return v;
}

// ---------------------------------------------------------------------------
// Kernel 1: gi_table[dir][v][j] = emb[v] @ Wih_dir[j].T + bih_dir[j]
// Only 64 distinct tokens -> whole input projection is a 64x384 table.
// ---------------------------------------------------------------------------
__global__ __launch_bounds__(G3, 1)
void gi_table_kernel(const float* __restrict__ emb,
                     const float* __restrict__ Wih_f, const float* __restrict__ bih_f,
                     const float* __restrict__ Wih_b, const float* __restrict__ bih_b,
                     float* __restrict__ gi_ws) {
  const int gid = blockIdx.x;          // 0..127
  const int dir = gid >> 6;
  const int v   = gid & 63;
  const int j   = threadIdx.x;         // 0..383
  const float* Wih = dir ? Wih_b : Wih_f;
  const float* bih = dir ? bih_b : bih_f;
  const float4* er = reinterpret_cast<const float4*>(emb + v * HH);
  const float4* wr = reinterpret_cast<const float4*>(Wih + j * HH);
  float acc = bih[j];
  #pragma unroll 8
  for (int k = 0; k < HH / 4; ++k) {
    float4 e = er[k];
    float4 w = wr[k];
    acc = fmaf(e.x, w.x, acc);
    acc = fmaf(e.y, w.y, acc);
    acc = fmaf(e.z, w.z, acc);
    acc = fmaf(e.w, w.w, acc);
  }
  gi_ws[dir * (VV * G3) + v * G3 + j] = acc;
}

// ---------------------------------------------------------------------------
// Kernel 2: recurrence. One block per (batch,dir) chain: 64 blocks x 512 thr.
// Quad layout: lane quad owns h-index i = wave*16 + quad; lane p=lane&3 owns
// k-slice p*32..p*32+31 (chunk-rotated for bank-conflict-free broadcasts).
// Each lane: 3 gate partial dots (96 FMAs, 3 indep chains) -> DPP quad
// reduce -> all 4 lanes redundantly do gate math (no exchange, no divergence)
// -> p==0 writes h to the OTHER h buffer. ONE barrier per step.
// ---------------------------------------------------------------------------
__global__ __launch_bounds__(512, 2)
void gru_kernel(const int* __restrict__ tokens, const int* __restrict__ lengths,
                const float* __restrict__ Whh_f, const float* __restrict__ bhh_f,
                const float* __restrict__ Whh_b, const float* __restrict__ bhh_b,
                const float* __restrict__ gi_ws, float* __restrict__ out) {
  __shared__ float giL[VV * G3];                 // 96 KB
  __shared__ int   tokL[TT];                     // 8 KB
  __shared__ __align__(16) float hbuf[2][HD];    // double-buffered h state

  const int bid  = blockIdx.x;    // 0..63
  const int b    = bid & 31;
  const int dir  = bid >> 5;
  const int tid  = threadIdx.x;   // 0..511
  const int wave = tid >> 6;
  const int lane = tid & 63;
  const int quad = lane >> 2;
  const int p    = lane & 3;
  const int i    = wave * 16 + quad;  // 0..127: this quad's h index

  int len = lengths[b];
  if (len < 1) len = 1;

  // Stage gi table + (reversed-if-bwd) token stream.
  const float* gi_src = gi_ws + dir * (VV * G3);
  for (int idx = tid; idx < VV * G3; idx += 512) giL[idx] = gi_src[idx];
  const int* tb = tokens + b * TT;
  for (int s = tid; s < len; s += 512) tokL[s] = tb[dir ? (len - 1 - s) : s];
  if (tid < HD) hbuf[0][tid] = 0.0f;

  // Per-thread weights: Whh rows {i, 128+i, 256+i}, k-slice p*32.. (rotated).
  const float* Whh = dir ? Whh_b : Whh_f;
  const float* bhh = dir ? bhh_b : bhh_f;
  float4 w4[3][8];
  #pragma unroll
  for (int g = 0; g < 3; ++g) {
    const float4* wr = reinterpret_cast<const float4*>(Whh + (g * HD + i) * HD);
    #pragma unroll
    for (int c = 0; c < 8; ++c) {
      const int k4 = p * 8 + ((c + 2 * p) & 7);  // rotated float4 index
      w4[g][c] = wr[k4];
    }
  }
  const float bhr = bhh[i], bhz = bhh[HD + i], bhn = bhh[2 * HD + i];

  __syncthreads();

  float h = 0.0f, hsum = 0.0f;

  #pragma unroll 2
  for (int s = 0; s < len; ++s) {
    const int cur = s & 1;
    const int tok = tokL[s];  // uniform broadcast
    const float* gi = giL + tok * G3;
    const float gir = gi[i];            // independent of h: issue early
    const float giz = gi[HD + i];
    const float gin = gi[2 * HD + i];

    // Partial dots over this lane's k-quarter (rotated chunks, conflict-free).
    float accr = bhr, accz = bhz, accn = bhn;
    const float4* hb4 = reinterpret_cast<const float4*>(&hbuf[cur][0]);
    #pragma unroll
    for (int c = 0; c < 8; ++c) {
      const float4 hv = hb4[p * 8 + ((c + 2 * p) & 7)];
      accr = fmaf(w4[0][c].x, hv.x, accr);
      accr = fmaf(w4[0][c].y, hv.y, accr);
      accr = fmaf(w4[0][c].z, hv.z, accr);
      accr = fmaf(w4[0][c].w, hv.w, accr);
      accz = fmaf(w4[1][c].x, hv.x, accz);
      accz = fmaf(w4[1][c].y, hv.y, accz);
      accz = fmaf(w4[1][c].z, hv.z, accz);
      accz = fmaf(w4[1][c].w, hv.w, accz);
      accn = fmaf(w4[2][c].x, hv.x, accn);
      accn = fmaf(w4[2][c].y, hv.y, accn);
      accn = fmaf(w4[2][c].z, hv.z, accn);
      accn = fmaf(w4[2][c].w, hv.w, accn);
    }
    accr = quad_reduce_add(accr);
    accz = quad_reduce_add(accz);
    accn = quad_reduce_add(accn);

    // All 4 lanes compute identical gate math (deterministic, no divergence).
    const float r = fsigmoid(gir + accr);
    const float z = fsigmoid(giz + accz);
    const float n = ftanh(gin + r * accn);
    h = (1.0f - z) * n + z * h;
    hsum += h;
    if (p == 0) hbuf[cur ^ 1][i] = h;
    __syncthreads();  // the only barrier per step (h double-buffered)
  }

  if (p == 0) out[b * HH + dir * HD + i] = hsum / (float)len;
}

// ---------------------------------------------------------------------------
extern "C" void kernel_launch(void* const* d_in, const int* in_sizes, int n_in,
                              void* d_out, int out_size, void* d_ws, size_t ws_size,
                              hipStream_t stream) {
  const int*   tokens  = (const int*)d_in[0];
  const int*   lengths = (const int*)d_in[1];
  const float* emb     = (const float*)d_in[2];
  const float* Wih_f   = (const float*)d_in[3];
  const float* Whh_f   = (const float*)d_in[4];
  const float* bih_f   = (const float*)d_in[5];
  const float* bhh_f   = (const float*)d_in[6];
  const float* Wih_b   = (const float*)d_in[7];
  const float* Whh_b   = (const float*)d_in[8];
  const float* bih_b   = (const float*)d_in[9];
  const float* bhh_b   = (const float*)d_in[10];
  float* out   = (float*)d_out;
  float* gi_ws = (float*)d_ws;  // 2*64*384*4 = 192 KB

  gi_table_kernel<<<2 * VV, G3, 0, stream>>>(emb, Wih_f, bih_f, Wih_b, bih_b, gi_ws);
  gru_kernel<<<2 * BB, 512, 0, stream>>>(tokens, lengths, Whh_f, bhh_f, Whh_b, bhh_b,
                                         gi_ws, out);
}

// Round 3
// 949.684 us; speedup vs baseline: 1.9053x; 1.0222x over previous
//
#include <hip/hip_runtime.h>

// Problem constants: B=32, T=2048, V=64, H=256, HD=128.
#define BB 32
#define TT 2048
#define VV 64
#define HH 256
#define HD 128
#define G3 384  // 3*HD

typedef _Float16 h2 __attribute__((ext_vector_type(2)));
typedef _Float16 h8 __attribute__((ext_vector_type(8)));

// ---------------------------------------------------------------------------
// Fast gate math (v_exp_f32 + v_rcp_f32; threshold is 3.8e-3, these are ~1ulp)
// ---------------------------------------------------------------------------
__device__ __forceinline__ float fsigmoid(float x) {
  return __builtin_amdgcn_rcpf(1.0f + __expf(-x));
}
__device__ __forceinline__ float ftanh(float x) {
  float ax = fabsf(x);
  float t = __expf(-2.0f * ax);  // in (0,1], no overflow
  float r = 1.0f - 2.0f * t * __builtin_amdgcn_rcpf(1.0f + t);
  return copysignf(r, x);
}

// Quad sum via DPP quad_perm — VALU pipe, all 4 lanes get the full sum.
__device__ __forceinline__ float quad_reduce_add(float v) {
  int x = __builtin_amdgcn_mov_dpp(__float_as_int(v), 0xB1, 0xF, 0xF, true);
  v += __int_as_float(x);
  x = __builtin_amdgcn_mov_dpp(__float_as_int(v), 0x4E, 0xF, 0xF, true);
  v += __int_as_float(x);
  return v;
}

template <int D>
__device__ __forceinline__ h2 getpair(h8 v) {
  return __builtin_shufflevector(v, v, 2 * D, 2 * D + 1);
}

// ---------------------------------------------------------------------------
// Kernel 1: gi_table[dir][v][j] = emb[v] @ Wih_dir[j].T + bih_dir[j]  (fp32)
// ---------------------------------------------------------------------------
__global__ __launch_bounds__(G3, 1)
void gi_table_kernel(const float* __restrict__ emb,
                     const float* __restrict__ Wih_f, const float* __restrict__ bih_f,
                     const float* __restrict__ Wih_b, const float* __restrict__ bih_b,
                     float* __restrict__ gi_ws) {
  const int gid = blockIdx.x;          // 0..127
  const int dir = gid >> 6;
  const int v   = gid & 63;
  const int j   = threadIdx.x;         // 0..383
  const float* Wih = dir ? Wih_b : Wih_f;
  const float* bih = dir ? bih_b : bih_f;
  const float4* er = reinterpret_cast<const float4*>(emb + v * HH);
  const float4* wr = reinterpret_cast<const float4*>(Wih + j * HH);
  float acc = bih[j];
  #pragma unroll 8
  for (int k = 0; k < HH / 4; ++k) {
    float4 e = er[k];
    float4 w = wr[k];
    acc = fmaf(e.x, w.x, acc);
    acc = fmaf(e.y, w.y, acc);
    acc = fmaf(e.z, w.z, acc);
    acc = fmaf(e.w, w.w, acc);
  }
  gi_ws[dir * (VV * G3) + v * G3 + j] = acc;
}

// ---------------------------------------------------------------------------
// Kernel 2: recurrence. 64 blocks (one per (b,dir)) x 512 threads.
// Quad layout: quad owns h-index i = wave*16+quad; lane p=lane&3 owns k-slice
// [32p,32p+32). Recurrent matvec in packed fp16 via v_dot2_f32_f16 (fp32
// accumulate); h master state stays fp32 in registers. h broadcast through
// LDS as fp16 (half traffic), chunk-rotated so every ds_read_b128 is
// bank-conflict-free. gi/token reads software-pipelined one step ahead.
// ---------------------------------------------------------------------------
__global__ __launch_bounds__(512, 2)
void gru_kernel(const int* __restrict__ tokens, const int* __restrict__ lengths,
                const float* __restrict__ Whh_f, const float* __restrict__ bhh_f,
                const float* __restrict__ Whh_b, const float* __restrict__ bhh_b,
                const float* __restrict__ gi_ws, float* __restrict__ out) {
  __shared__ float giL[VV * G3];                        // 96 KB
  __shared__ int   tokL[TT];                            // 8 KB
  __shared__ __align__(16) _Float16 hbufh[2][HD];       // fp16 h, double-buffered

  const int bid  = blockIdx.x;    // 0..63
  const int b    = bid & 31;
  const int dir  = bid >> 5;
  const int tid  = threadIdx.x;   // 0..511
  const int wave = tid >> 6;
  const int lane = tid & 63;
  const int quad = lane >> 2;
  const int p    = lane & 3;
  const int i    = wave * 16 + quad;  // 0..127

  int len = lengths[b];
  if (len < 1) len = 1;

  // Stage gi table + (reversed-if-bwd) token stream.
  const float* gi_src = gi_ws + dir * (VV * G3);
  for (int idx = tid; idx < VV * G3; idx += 512) giL[idx] = gi_src[idx];
  const int* tb = tokens + b * TT;
  for (int s = tid; s < len; s += 512) tokL[s] = tb[dir ? (len - 1 - s) : s];
  if (tid < HD) hbufh[0][tid] = (_Float16)0.0f;

  // Whh rows {i,128+i,256+i}, k-slice [32p,32p+32) as packed fp16, chunk-
  // rotated: logical chunk c holds data of chunk cr=(c+p)&3 (8 halves).
  const float* Whh = dir ? Whh_b : Whh_f;
  const float* bhh = dir ? bhh_b : bhh_f;
  h8 w8[3][4];
  #pragma unroll
  for (int g = 0; g < 3; ++g) {
    const float* wr = Whh + (g * HD + i) * HD + p * 32;
    #pragma unroll
    for (int c = 0; c < 4; ++c) {
      const int kb = ((c + p) & 3) * 8;
      h8 w;
      #pragma unroll
      for (int d = 0; d < 8; ++d) w[d] = (_Float16)wr[kb + d];
      w8[g][c] = w;
    }
  }
  const float bhr = bhh[i], bhz = bhh[HD + i], bhn = bhh[2 * HD + i];

  __syncthreads();

  float h = 0.0f, hsum = 0.0f;

  // Prefetch gi for step 0 (h-independent).
  int tok = tokL[0];
  float gir = giL[tok * G3 + i];
  float giz = giL[tok * G3 + HD + i];
  float gin = giL[tok * G3 + 2 * HD + i];

#define DOT8(acc, wv, hv)                                            \
  acc = __builtin_amdgcn_fdot2(getpair<0>(wv), getpair<0>(hv), acc, false); \
  acc = __builtin_amdgcn_fdot2(getpair<1>(wv), getpair<1>(hv), acc, false); \
  acc = __builtin_amdgcn_fdot2(getpair<2>(wv), getpair<2>(hv), acc, false); \
  acc = __builtin_amdgcn_fdot2(getpair<3>(wv), getpair<3>(hv), acc, false)

  #pragma unroll 2
  for (int s = 0; s < len; ++s) {
    const int cur = s & 1;
    const h8* hb8 = reinterpret_cast<const h8*>(&hbufh[cur][0]);

    float accr = bhr, accz = bhz, accn = bhn;
    #pragma unroll
    for (int c = 0; c < 4; ++c) {
      const h8 hv = hb8[p * 4 + ((c + p) & 3)];  // rotated: conflict-free b128
      DOT8(accr, w8[0][c], hv);
      DOT8(accz, w8[1][c], hv);
      DOT8(accn, w8[2][c], hv);
    }

    // Prefetch next step's token + gi while dots are in flight.
    const int sn = (s + 1 < len) ? (s + 1) : 0;
    const int ntok = tokL[sn];
    const float ngir = giL[ntok * G3 + i];
    const float ngiz = giL[ntok * G3 + HD + i];
    const float ngin = giL[ntok * G3 + 2 * HD + i];

    accr = quad_reduce_add(accr);
    accz = quad_reduce_add(accz);
    accn = quad_reduce_add(accn);

    // All 4 lanes compute identical gate math (no divergence, no exchange).
    const float r = fsigmoid(gir + accr);
    const float z = fsigmoid(giz + accz);
    const float n = ftanh(gin + r * accn);
    h = (1.0f - z) * n + z * h;
    hsum += h;
    if (p == 0) hbufh[cur ^ 1][i] = (_Float16)h;
    __syncthreads();  // single barrier per step (double-buffered h)

    gir = ngir; giz = ngiz; gin = ngin;
  }
#undef DOT8

  if (p == 0) out[b * HH + dir * HD + i] = hsum / (float)len;
}

// ---------------------------------------------------------------------------
extern "C" void kernel_launch(void* const* d_in, const int* in_sizes, int n_in,
                              void* d_out, int out_size, void* d_ws, size_t ws_size,
                              hipStream_t stream) {
  const int*   tokens  = (const int*)d_in[0];
  const int*   lengths = (const int*)d_in[1];
  const float* emb     = (const float*)d_in[2];
  const float* Wih_f   = (const float*)d_in[3];
  const float* Whh_f   = (const float*)d_in[4];
  const float* bih_f   = (const float*)d_in[5];
  const float* bhh_f   = (const float*)d_in[6];
  const float* Wih_b   = (const float*)d_in[7];
  const float* Whh_b   = (const float*)d_in[8];
  const float* bih_b   = (const float*)d_in[9];
  const float* bhh_b   = (const float*)d_in[10];
  float* out   = (float*)d_out;
  float* gi_ws = (float*)d_ws;  // 2*64*384*4 = 192 KB

  gi_table_kernel<<<2 * VV, G3, 0, stream>>>(emb, Wih_f, bih_f, Wih_b, bih_b, gi_ws);
  gru_kernel<<<2 * BB, 512, 0, stream>>>(tokens, lengths, Whh_f, bhh_f, Whh_b, bhh_b,
                                         gi_ws, out);
}

// Round 4
// 852.164 us; speedup vs baseline: 2.1233x; 1.1144x over previous
//
#include <hip/hip_runtime.h>

// Problem constants: B=32, T=2048, V=64, H=256, HD=128.
#define BB 32
#define TT 2048
#define VV 64
#define HH 256
#define HD 128
#define G3 384  // 3*HD

typedef _Float16 h2 __attribute__((ext_vector_type(2)));
typedef _Float16 h8 __attribute__((ext_vector_type(8)));

// exp2-domain scales: sigmoid(a)=rcp(1+2^(-a*log2e)), tanh(a)=1-2*rcp(1+2^(2a*log2e))
#define SRZ (-1.4426950408889634f)  // -log2(e), for r and z gates
#define SN  (2.8853900817779268f)   // +2*log2(e), for n gate

// Quad sum via DPP quad_perm — VALU pipe, all 4 lanes get the full sum.
__device__ __forceinline__ float quad_reduce_add(float v) {
  int x = __builtin_amdgcn_mov_dpp(__float_as_int(v), 0xB1, 0xF, 0xF, true);
  v += __int_as_float(x);
  x = __builtin_amdgcn_mov_dpp(__float_as_int(v), 0x4E, 0xF, 0xF, true);
  v += __int_as_float(x);
  return v;
}

template <int D>
__device__ __forceinline__ h2 getpair(h8 v) {
  return __builtin_shufflevector(v, v, 2 * D, 2 * D + 1);
}

// ---------------------------------------------------------------------------
// Kernel 1: gi_table[dir][v][j] = (emb[v] @ Wih_dir[j].T + bih_dir[j]) * scale_j
// scale: rows [0,256) (r,z) by -log2e; rows [256,384) (n) by +2log2e.
// ---------------------------------------------------------------------------
__global__ __launch_bounds__(G3, 1)
void gi_table_kernel(const float* __restrict__ emb,
                     const float* __restrict__ Wih_f, const float* __restrict__ bih_f,
                     const float* __restrict__ Wih_b, const float* __restrict__ bih_b,
                     float* __restrict__ gi_ws) {
  const int gid = blockIdx.x;          // 0..127
  const int dir = gid >> 6;
  const int v   = gid & 63;
  const int j   = threadIdx.x;         // 0..383
  const float* Wih = dir ? Wih_b : Wih_f;
  const float* bih = dir ? bih_b : bih_f;
  const float4* er = reinterpret_cast<const float4*>(emb + v * HH);
  const float4* wr = reinterpret_cast<const float4*>(Wih + j * HH);
  float acc = bih[j];
  #pragma unroll 8
  for (int k = 0; k < HH / 4; ++k) {
    float4 e = er[k];
    float4 w = wr[k];
    acc = fmaf(e.x, w.x, acc);
    acc = fmaf(e.y, w.y, acc);
    acc = fmaf(e.z, w.z, acc);
    acc = fmaf(e.w, w.w, acc);
  }
  const float sc = (j < 2 * HD) ? SRZ : SN;
  gi_ws[dir * (VV * G3) + v * G3 + j] = acc * sc;
}

// ---------------------------------------------------------------------------
// Kernel 2: recurrence. 64 blocks x 256 threads (4 waves, 1 per SIMD).
// Quad q (= wave*16 + quad) owns h-indices i0=2q, i1=2q+1; lane p=lane&3 owns
// k-slice [32p,32p+32), chunk-rotated so each quad's 4 ds_read_b128 hit
// disjoint banks (and broadcast across quads). 6 accumulators (2 outputs x 3
// gates) per lane -> 2-op DPP quad reduce each -> all 4 lanes redundantly do
// exp2-domain gate math -> p==0 packs (h0,h1) to one dword in the other h
// buffer. ONE barrier/step. Token prefetched 2 steps ahead, gi 1 step ahead.
// ---------------------------------------------------------------------------
__global__ __launch_bounds__(256, 1)
void gru_kernel(const int* __restrict__ tokens, const int* __restrict__ lengths,
                const float* __restrict__ Whh_f, const float* __restrict__ bhh_f,
                const float* __restrict__ Whh_b, const float* __restrict__ bhh_b,
                const float* __restrict__ gi_ws, float* __restrict__ out) {
  __shared__ float giL[VV * G3];                   // 96 KB (pre-scaled)
  __shared__ int   tokL[TT];                       // 8 KB
  __shared__ __align__(16) _Float16 hbufh[2][HD];  // fp16 h, double-buffered

  const int bid  = blockIdx.x;    // 0..63
  const int b    = bid & 31;
  const int dir  = bid >> 5;
  const int tid  = threadIdx.x;   // 0..255
  const int wave = tid >> 6;
  const int lane = tid & 63;
  const int quad = lane >> 2;
  const int p    = lane & 3;
  const int q    = wave * 16 + quad;  // 0..63
  const int i0   = 2 * q;             // owned h indices: i0, i0+1

  int len = lengths[b];
  if (len < 1) len = 1;

  // Stage gi table + (reversed-if-bwd) token stream.
  const float* gi_src = gi_ws + dir * (VV * G3);
  for (int idx = tid; idx < VV * G3; idx += 256) giL[idx] = gi_src[idx];
  const int* tb = tokens + b * TT;
  for (int s = tid; s < len; s += 256) tokL[s] = tb[dir ? (len - 1 - s) : s];
  if (tid < HD) hbufh[0][tid] = (_Float16)0.0f;

  // Weights: rows {g*HD+i0, g*HD+i0+1}, k-slice [32p,32p+32), chunk-rotated
  // (logical chunk c holds k-block ((c+p)&3)*8), pre-scaled into exp2 domain.
  const float* Whh = dir ? Whh_b : Whh_f;
  const float* bhh = dir ? bhh_b : bhh_f;
  h8 w8[3][2][4];
  #pragma unroll
  for (int g = 0; g < 3; ++g) {
    const float sc = (g < 2) ? SRZ : SN;
    #pragma unroll
    for (int o = 0; o < 2; ++o) {
      const float* wr = Whh + (g * HD + i0 + o) * HD + p * 32;
      #pragma unroll
      for (int c = 0; c < 4; ++c) {
        const int kb = ((c + p) & 3) * 8;
        h8 w;
        #pragma unroll
        for (int d = 0; d < 8; ++d) w[d] = (_Float16)(wr[kb + d] * sc);
        w8[g][o][c] = w;
      }
    }
  }
  const float bhr0 = bhh[i0] * SRZ,          bhr1 = bhh[i0 + 1] * SRZ;
  const float bhz0 = bhh[HD + i0] * SRZ,     bhz1 = bhh[HD + i0 + 1] * SRZ;
  const float bhn0 = bhh[2 * HD + i0] * SN,  bhn1 = bhh[2 * HD + i0 + 1] * SN;

  __syncthreads();

  float h0 = 0.0f, h1 = 0.0f, hsum0 = 0.0f, hsum1 = 0.0f;

  // gi prefetch pipeline: gi for step s in regs; ntok = token for step s+1.
  const float2* giL2 = reinterpret_cast<const float2*>(giL);
  int tok0 = tokL[0];
  float2 gr = giL2[(tok0 * G3) / 2 + q];            // {gi_r[i0], gi_r[i0+1]}
  float2 gz = giL2[(tok0 * G3 + HD) / 2 + q];
  float2 gn = giL2[(tok0 * G3 + 2 * HD) / 2 + q];
  int ntok = tokL[(1 < len) ? 1 : 0];

#define DOT8(acc, wv, hv)                                                   \
  acc = __builtin_amdgcn_fdot2(getpair<0>(wv), getpair<0>(hv), acc, false); \
  acc = __builtin_amdgcn_fdot2(getpair<1>(wv), getpair<1>(hv), acc, false); \
  acc = __builtin_amdgcn_fdot2(getpair<2>(wv), getpair<2>(hv), acc, false); \
  acc = __builtin_amdgcn_fdot2(getpair<3>(wv), getpair<3>(hv), acc, false)

  #pragma unroll 2
  for (int s = 0; s < len; ++s) {
    const int cur = s & 1;
    const h8* hb8 = reinterpret_cast<const h8*>(&hbufh[cur][0]);

    // All four h reads issue back-to-back right after the barrier.
    const h8 hv0 = hb8[p * 4 + ((0 + p) & 3)];
    const h8 hv1 = hb8[p * 4 + ((1 + p) & 3)];
    const h8 hv2 = hb8[p * 4 + ((2 + p) & 3)];
    const h8 hv3 = hb8[p * 4 + ((3 + p) & 3)];

    // Prefetch next step's gi (from ntok) and the token after that.
    const float2 ngr = giL2[(ntok * G3) / 2 + q];
    const float2 ngz = giL2[(ntok * G3 + HD) / 2 + q];
    const float2 ngn = giL2[(ntok * G3 + 2 * HD) / 2 + q];
    const int s2 = (s + 2 < len) ? (s + 2) : (len - 1);
    const int nntok = tokL[s2];

    float ar0 = bhr0, ar1 = bhr1, az0 = bhz0, az1 = bhz1, an0 = bhn0, an1 = bhn1;
    DOT8(ar0, w8[0][0][0], hv0); DOT8(ar1, w8[0][1][0], hv0);
    DOT8(az0, w8[1][0][0], hv0); DOT8(az1, w8[1][1][0], hv0);
    DOT8(an0, w8[2][0][0], hv0); DOT8(an1, w8[2][1][0], hv0);
    DOT8(ar0, w8[0][0][1], hv1); DOT8(ar1, w8[0][1][1], hv1);
    DOT8(az0, w8[1][0][1], hv1); DOT8(az1, w8[1][1][1], hv1);
    DOT8(an0, w8[2][0][1], hv1); DOT8(an1, w8[2][1][1], hv1);
    DOT8(ar0, w8[0][0][2], hv2); DOT8(ar1, w8[0][1][2], hv2);
    DOT8(az0, w8[1][0][2], hv2); DOT8(az1, w8[1][1][2], hv2);
    DOT8(an0, w8[2][0][2], hv2); DOT8(an1, w8[2][1][2], hv2);
    DOT8(ar0, w8[0][0][3], hv3); DOT8(ar1, w8[0][1][3], hv3);
    DOT8(az0, w8[1][0][3], hv3); DOT8(az1, w8[1][1][3], hv3);
    DOT8(an0, w8[2][0][3], hv3); DOT8(an1, w8[2][1][3], hv3);

    ar0 = quad_reduce_add(ar0); ar1 = quad_reduce_add(ar1);
    az0 = quad_reduce_add(az0); az1 = quad_reduce_add(az1);
    an0 = quad_reduce_add(an0); an1 = quad_reduce_add(an1);

    // exp2-domain gates (overflow-safe at both ends; rcp(inf)=0).
    const float r0 = __builtin_amdgcn_rcpf(1.0f + __builtin_amdgcn_exp2f(gr.x + ar0));
    const float r1 = __builtin_amdgcn_rcpf(1.0f + __builtin_amdgcn_exp2f(gr.y + ar1));
    const float z0 = __builtin_amdgcn_rcpf(1.0f + __builtin_amdgcn_exp2f(gz.x + az0));
    const float z1 = __builtin_amdgcn_rcpf(1.0f + __builtin_amdgcn_exp2f(gz.y + az1));
    const float n0 = 1.0f - 2.0f * __builtin_amdgcn_rcpf(1.0f + __builtin_amdgcn_exp2f(gn.x + r0 * an0));
    const float n1 = 1.0f - 2.0f * __builtin_amdgcn_rcpf(1.0f + __builtin_amdgcn_exp2f(gn.y + r1 * an1));
    h0 = (1.0f - z0) * n0 + z0 * h0;
    h1 = (1.0f - z1) * n1 + z1 * h1;
    hsum0 += h0;
    hsum1 += h1;
    if (p == 0) {
      h2 hpk;
      hpk.x = (_Float16)h0;
      hpk.y = (_Float16)h1;
      reinterpret_cast<h2*>(&hbufh[cur ^ 1][0])[q] = hpk;
    }
    __syncthreads();  // single barrier per step (double-buffered h)

    gr = ngr; gz = ngz; gn = ngn; ntok = nntok;
  }
#undef DOT8

  if (p == 0) {
    const float inv = 1.0f / (float)len;
    float2 o2;
    o2.x = hsum0 * inv;
    o2.y = hsum1 * inv;
    reinterpret_cast<float2*>(out + b * HH + dir * HD)[q] = o2;
  }
}

// ---------------------------------------------------------------------------
extern "C" void kernel_launch(void* const* d_in, const int* in_sizes, int n_in,
                              void* d_out, int out_size, void* d_ws, size_t ws_size,
                              hipStream_t stream) {
  const int*   tokens  = (const int*)d_in[0];
  const int*   lengths = (const int*)d_in[1];
  const float* emb     = (const float*)d_in[2];
  const float* Wih_f   = (const float*)d_in[3];
  const float* Whh_f   = (const float*)d_in[4];
  const float* bih_f   = (const float*)d_in[5];
  const float* bhh_f   = (const float*)d_in[6];
  const float* Wih_b   = (const float*)d_in[7];
  const float* Whh_b   = (const float*)d_in[8];
  const float* bih_b   = (const float*)d_in[9];
  const float* bhh_b   = (const float*)d_in[10];
  float* out   = (float*)d_out;
  float* gi_ws = (float*)d_ws;  // 2*64*384*4 = 192 KB

  gi_table_kernel<<<2 * VV, G3, 0, stream>>>(emb, Wih_f, bih_f, Wih_b, bih_b, gi_ws);
  gru_kernel<<<2 * BB, 256, 0, stream>>>(tokens, lengths, Whh_f, bhh_f, Whh_b, bhh_b,
                                         gi_ws, out);
}

// Round 5
// 803.773 us; speedup vs baseline: 2.2511x; 1.0602x over previous
//
#include <hip/hip_runtime.h>

// Problem constants: B=32, T=2048, V=64, H=256, HD=128.
#define BB 32
#define TT 2048
#define VV 64
#define HH 256
#define HD 128
#define G3 384  // 3*HD

typedef _Float16 h2 __attribute__((ext_vector_type(2)));
typedef _Float16 h8 __attribute__((ext_vector_type(8)));

// exp2-domain scales: sigmoid(a)=rcp(1+2^(-a*log2e)), tanh(a)=1-2*rcp(1+2^(2a*log2e))
#define SRZ (-1.4426950408889634f)  // -log2(e), r/z gates
#define SN  (2.8853900817779268f)   // +2*log2(e), n gate

// Pair sum: swap with the other lane of the pair (quad_perm[1,0,3,2]=0xB1), add.
__device__ __forceinline__ float pair_reduce_add(float v) {
  int x = __builtin_amdgcn_mov_dpp(__float_as_int(v), 0xB1, 0xF, 0xF, true);
  return v + __int_as_float(x);
}

template <int D>
__device__ __forceinline__ h2 getpair(h8 v) {
  return __builtin_shufflevector(v, v, 2 * D, 2 * D + 1);
}

// ---------------------------------------------------------------------------
// Kernel 1: gi_table[dir][v][j] = (emb[v] @ Wih_dir[j].T + bih_dir[j]) * scale_j
// ---------------------------------------------------------------------------
__global__ __launch_bounds__(G3, 1)
void gi_table_kernel(const float* __restrict__ emb,
                     const float* __restrict__ Wih_f, const float* __restrict__ bih_f,
                     const float* __restrict__ Wih_b, const float* __restrict__ bih_b,
                     float* __restrict__ gi_ws) {
  const int gid = blockIdx.x;          // 0..127
  const int dir = gid >> 6;
  const int v   = gid & 63;
  const int j   = threadIdx.x;         // 0..383
  const float* Wih = dir ? Wih_b : Wih_f;
  const float* bih = dir ? bih_b : bih_f;
  const float4* er = reinterpret_cast<const float4*>(emb + v * HH);
  const float4* wr = reinterpret_cast<const float4*>(Wih + j * HH);
  float acc = bih[j];
  #pragma unroll 8
  for (int k = 0; k < HH / 4; ++k) {
    float4 e = er[k];
    float4 w = wr[k];
    acc = fmaf(e.x, w.x, acc);
    acc = fmaf(e.y, w.y, acc);
    acc = fmaf(e.z, w.z, acc);
    acc = fmaf(e.w, w.w, acc);
  }
  const float sc = (j < 2 * HD) ? SRZ : SN;
  gi_ws[dir * (VV * G3) + v * G3 + j] = acc * sc;
}

// ---------------------------------------------------------------------------
// Kernel 2: recurrence. 64 blocks x 256 threads (4 waves, 1/SIMD).
// Pair (2 lanes) owns h-index i = wave*32 + (lane>>1); lane kh=lane&1 owns
// k-half [64kh, 64kh+64) (8 x ds_read_b128). h is kept in TWO per-k-half
// copies, 320B apart (16-bank shift): reads are 2 broadcast addresses on
// disjoint bank halves, writes are 2-way on disjoint halves -> all free,
// no predication. 3 accumulators -> 1-stage DPP pair reduce -> exp2-domain
// gates (both lanes redundant) -> b16 write to other buffer. 1 barrier/step.
// Token offsets pre-multiplied by 384 at staging; gi prefetched 1 step ahead,
// token 2 ahead.
// ---------------------------------------------------------------------------
__global__ __launch_bounds__(256, 1)
void gru_kernel(const int* __restrict__ tokens, const int* __restrict__ lengths,
                const float* __restrict__ Whh_f, const float* __restrict__ bhh_f,
                const float* __restrict__ Whh_b, const float* __restrict__ bhh_b,
                const float* __restrict__ gi_ws, float* __restrict__ out) {
  __shared__ float giL[VV * G3];                    // 96 KB (pre-scaled)
  __shared__ int   tokL[TT];                        // 8 KB (tok*384)
  __shared__ __align__(16) _Float16 hb[2][2][160];  // [dbuf][khalf-copy][128+32 pad]

  const int bid  = blockIdx.x;    // 0..63
  const int b    = bid & 31;
  const int dir  = bid >> 5;
  const int tid  = threadIdx.x;   // 0..255
  const int wave = tid >> 6;
  const int lane = tid & 63;
  const int kh   = lane & 1;            // k-half
  const int i    = wave * 32 + (lane >> 1);  // owned h index 0..127

  int len = lengths[b];
  if (len < 1) len = 1;

  // Stage gi table (float4), token offsets (pre-multiplied), zero h buffers.
  {
    const float4* gs = reinterpret_cast<const float4*>(gi_ws + dir * (VV * G3));
    float4* gd = reinterpret_cast<float4*>(giL);
    for (int idx = tid; idx < VV * G3 / 4; idx += 256) gd[idx] = gs[idx];
    const int* tb = tokens + b * TT;
    for (int s = tid; s < len; s += 256) tokL[s] = tb[dir ? (len - 1 - s) : s] * G3;
    _Float16* hz = reinterpret_cast<_Float16*>(hb);
    for (int idx = tid; idx < 2 * 2 * 160; idx += 256) hz[idx] = (_Float16)0.0f;
  }

  // Weights: rows {i, 128+i, 256+i}, k-half [64kh,64kh+64), exp2-pre-scaled.
  const float* Whh = dir ? Whh_b : Whh_f;
  const float* bhh = dir ? bhh_b : bhh_f;
  h8 w8[3][8];
  #pragma unroll
  for (int g = 0; g < 3; ++g) {
    const float sc = (g < 2) ? SRZ : SN;
    const float* wr = Whh + (g * HD + i) * HD + kh * 64;
    #pragma unroll
    for (int c = 0; c < 8; ++c) {
      h8 w;
      #pragma unroll
      for (int d = 0; d < 8; ++d) w[d] = (_Float16)(wr[c * 8 + d] * sc);
      w8[g][c] = w;
    }
  }
  const float bhr = bhh[i] * SRZ;
  const float bhz = bhh[HD + i] * SRZ;
  const float bhn = bhh[2 * HD + i] * SN;

  __syncthreads();

  float h = 0.0f, hsum = 0.0f;

  int tokOff = tokL[0];
  float gr = giL[tokOff + i];
  float gz = giL[tokOff + HD + i];
  float gn = giL[tokOff + 2 * HD + i];
  int ntokOff = tokL[(1 < len) ? 1 : 0];

#define DOT8(acc, wv, hv)                                                   \
  acc = __builtin_amdgcn_fdot2(getpair<0>(wv), getpair<0>(hv), acc, false); \
  acc = __builtin_amdgcn_fdot2(getpair<1>(wv), getpair<1>(hv), acc, false); \
  acc = __builtin_amdgcn_fdot2(getpair<2>(wv), getpair<2>(hv), acc, false); \
  acc = __builtin_amdgcn_fdot2(getpair<3>(wv), getpair<3>(hv), acc, false)

  #pragma unroll 2
  for (int s = 0; s < len; ++s) {
    const int cur = s & 1;
    // This lane's k-half slice of h: 8 x b128, broadcast + disjoint banks.
    const h8* hv8 = reinterpret_cast<const h8*>(&hb[cur][kh][kh * 64]);
    const h8 hv0 = hv8[0], hv1 = hv8[1], hv2 = hv8[2], hv3 = hv8[3];
    const h8 hv4 = hv8[4], hv5 = hv8[5], hv6 = hv8[6], hv7 = hv8[7];

    // Prefetch next step's gi and the token offset after that.
    const float ngr = giL[ntokOff + i];
    const float ngz = giL[ntokOff + HD + i];
    const float ngn = giL[ntokOff + 2 * HD + i];
    int s2 = s + 2;
    if (s2 >= len) s2 = len - 1;
    const int nnOff = tokL[s2];

    float ar = bhr, az = bhz, an = bhn;
    DOT8(ar, w8[0][0], hv0); DOT8(az, w8[1][0], hv0); DOT8(an, w8[2][0], hv0);
    DOT8(ar, w8[0][1], hv1); DOT8(az, w8[1][1], hv1); DOT8(an, w8[2][1], hv1);
    DOT8(ar, w8[0][2], hv2); DOT8(az, w8[1][2], hv2); DOT8(an, w8[2][2], hv2);
    DOT8(ar, w8[0][3], hv3); DOT8(az, w8[1][3], hv3); DOT8(an, w8[2][3], hv3);
    DOT8(ar, w8[0][4], hv4); DOT8(az, w8[1][4], hv4); DOT8(an, w8[2][4], hv4);
    DOT8(ar, w8[0][5], hv5); DOT8(az, w8[1][5], hv5); DOT8(an, w8[2][5], hv5);
    DOT8(ar, w8[0][6], hv6); DOT8(az, w8[1][6], hv6); DOT8(an, w8[2][6], hv6);
    DOT8(ar, w8[0][7], hv7); DOT8(az, w8[1][7], hv7); DOT8(an, w8[2][7], hv7);

    ar = pair_reduce_add(ar);
    az = pair_reduce_add(az);
    an = pair_reduce_add(an);

    // exp2-domain gates (overflow-safe; rcp(inf)=0).
    const float r = __builtin_amdgcn_rcpf(1.0f + __builtin_amdgcn_exp2f(gr + ar));
    const float z = __builtin_amdgcn_rcpf(1.0f + __builtin_amdgcn_exp2f(gz + az));
    const float tn = __builtin_amdgcn_rcpf(1.0f + __builtin_amdgcn_exp2f(fmaf(r, an, gn)));
    const float n = fmaf(-2.0f, tn, 1.0f);
    h = fmaf(z, h - n, n);
    hb[cur ^ 1][kh][i] = (_Float16)h;  // disjoint bank halves per kh, 2-way
    hsum += h;
    __syncthreads();  // single barrier per step (double-buffered h)

    gr = ngr; gz = ngz; gn = ngn; ntokOff = nnOff;
  }
#undef DOT8

  if (!(lane & 1)) out[b * HH + dir * HD + i] = hsum / (float)len;
}

// ---------------------------------------------------------------------------
extern "C" void kernel_launch(void* const* d_in, const int* in_sizes, int n_in,
                              void* d_out, int out_size, void* d_ws, size_t ws_size,
                              hipStream_t stream) {
  const int*   tokens  = (const int*)d_in[0];
  const int*   lengths = (const int*)d_in[1];
  const float* emb     = (const float*)d_in[2];
  const float* Wih_f   = (const float*)d_in[3];
  const float* Whh_f   = (const float*)d_in[4];
  const float* bih_f   = (const float*)d_in[5];
  const float* bhh_f   = (const float*)d_in[6];
  const float* Wih_b   = (const float*)d_in[7];
  const float* Whh_b   = (const float*)d_in[8];
  const float* bih_b   = (const float*)d_in[9];
  const float* bhh_b   = (const float*)d_in[10];
  float* out   = (float*)d_out;
  float* gi_ws = (float*)d_ws;  // 2*64*384*4 = 192 KB

  gi_table_kernel<<<2 * VV, G3, 0, stream>>>(emb, Wih_f, bih_f, Wih_b, bih_b, gi_ws);
  gru_kernel<<<2 * BB, 256, 0, stream>>>(tokens, lengths, Whh_f, bhh_f, Whh_b, bhh_b,
                                         gi_ws, out);
}